// Round 3
// baseline (924.007 us; speedup 1.0000x reference)
//
#include <hip/hip_runtime.h>
#include <hip/hip_bf16.h>

#define NN 50000
#define EE 800000
#define ND 128
#define ED 32
#define HD 256

typedef __attribute__((ext_vector_type(8))) short bf16x8;
typedef __attribute__((ext_vector_type(4))) float f32x4;

__device__ __forceinline__ ushort f2b(float f) {
  union { float f; unsigned u; } v; v.f = f;
  return (ushort)((v.u + 0x7fffu + ((v.u >> 16) & 1u)) >> 16);
}

__device__ __forceinline__ ushort4 f2b4(float4 v) {
  return make_ushort4(f2b(v.x), f2b(v.y), f2b(v.z), f2b(v.w));
}

// One MFMA layer: in_lds [64 x KDIM] bf16 (stride in_stride), Wt [256 x KDIM] bf16
// (row-major, i.e. original W transposed), bias f32[256]. Output: ReLU, bf16 ->
// out_lds [64 x 256] (stride out_stride). in_lds/out_lds may alias (barriers inside).
template<int KDIM>
__device__ __forceinline__ void layer256(const ushort* __restrict__ in_lds, int in_stride,
                                         const ushort* __restrict__ wt,
                                         const float* __restrict__ bias,
                                         ushort* __restrict__ out_lds, int out_stride,
                                         int wave, int lane) {
  f32x4 acc[4][4] = {};
  const int c0 = wave * 64;
  const int kb = (lane >> 4) * 8;
  const int l15 = lane & 15;
  for (int ks = 0; ks < KDIM / 32; ++ks) {
    const int k = ks * 32 + kb;
    bf16x8 a[4], b[4];
#pragma unroll
    for (int m = 0; m < 4; ++m)
      a[m] = *reinterpret_cast<const bf16x8*>(in_lds + (m * 16 + l15) * in_stride + k);
#pragma unroll
    for (int n = 0; n < 4; ++n)
      b[n] = *reinterpret_cast<const bf16x8*>(wt + (size_t)(c0 + n * 16 + l15) * KDIM + k);
#pragma unroll
    for (int m = 0; m < 4; ++m)
#pragma unroll
      for (int n = 0; n < 4; ++n)
        acc[m][n] = __builtin_amdgcn_mfma_f32_16x16x32_bf16(a[m], b[n], acc[m][n], 0, 0, 0);
  }
  __syncthreads();  // all waves done reading in_lds (may alias out_lds)
#pragma unroll
  for (int n = 0; n < 4; ++n) {
    const int c = c0 + n * 16 + l15;
    const float bv = bias[c];
#pragma unroll
    for (int m = 0; m < 4; ++m)
#pragma unroll
      for (int j = 0; j < 4; ++j) {
        float v = acc[m][n][j] + bv;
        v = fmaxf(v, 0.f);
        out_lds[(m * 16 + (lane >> 4) * 4 + j) * out_stride + c] = f2b(v);
      }
  }
  __syncthreads();
}

__global__ __launch_bounds__(256) void edge_kernel(
    const float* __restrict__ x, const int* __restrict__ ei, const float* __restrict__ ea,
    const ushort* __restrict__ Wt1, const float* __restrict__ b1,
    const ushort* __restrict__ Wt2, const float* __restrict__ b2,
    const ushort* __restrict__ Wt3, const float* __restrict__ b3,
    float* __restrict__ aggr) {
  __shared__ __align__(16) ushort efs[64 * 296];
  __shared__ int rows_s[64], cols_s[64];
  const int tid = threadIdx.x;
  const int e0 = blockIdx.x * 64;
  if (tid < 64) {
    rows_s[tid] = ei[e0 + tid];
    cols_s[tid] = ei[EE + e0 + tid];
  }
  __syncthreads();
  {  // gather [x[row] | x[col] | edge_attr] -> efs bf16, 4 threads per edge
    const int el = tid >> 2, p = tid & 3;
    ushort* dst = efs + el * 296;
    const float4* xr = reinterpret_cast<const float4*>(x + (size_t)rows_s[el] * ND) + p * 8;
    const float4* xc = reinterpret_cast<const float4*>(x + (size_t)cols_s[el] * ND) + p * 8;
#pragma unroll
    for (int j = 0; j < 8; ++j)
      *reinterpret_cast<ushort4*>(dst + p * 32 + j * 4) = f2b4(xr[j]);
#pragma unroll
    for (int j = 0; j < 8; ++j)
      *reinterpret_cast<ushort4*>(dst + 128 + p * 32 + j * 4) = f2b4(xc[j]);
    const float4* eap = reinterpret_cast<const float4*>(ea + (size_t)(e0 + el) * ED) + p * 2;
#pragma unroll
    for (int j = 0; j < 2; ++j)
      *reinterpret_cast<ushort4*>(dst + 256 + p * 8 + j * 4) = f2b4(eap[j]);
  }
  __syncthreads();
  const int wave = tid >> 6, lane = tid & 63;
  layer256<288>(efs, 296, Wt1, b1, efs, 264, wave, lane);
  layer256<256>(efs, 264, Wt2, b2, efs, 264, wave, lane);
  {  // layer 3: [64 x 256] -> [64 x 128], then scatter-add to aggr[col]
    f32x4 acc[2][4] = {};
    const int r0 = (wave & 1) * 32;
    const int c0 = (wave >> 1) * 64;
    const int kb = (lane >> 4) * 8, l15 = lane & 15;
    for (int ks = 0; ks < 8; ++ks) {
      const int k = ks * 32 + kb;
      bf16x8 a[2], b[4];
#pragma unroll
      for (int m = 0; m < 2; ++m)
        a[m] = *reinterpret_cast<const bf16x8*>(efs + (r0 + m * 16 + l15) * 264 + k);
#pragma unroll
      for (int n = 0; n < 4; ++n)
        b[n] = *reinterpret_cast<const bf16x8*>(Wt3 + (size_t)(c0 + n * 16 + l15) * 256 + k);
#pragma unroll
      for (int m = 0; m < 2; ++m)
#pragma unroll
        for (int n = 0; n < 4; ++n)
          acc[m][n] = __builtin_amdgcn_mfma_f32_16x16x32_bf16(a[m], b[n], acc[m][n], 0, 0, 0);
    }
#pragma unroll
    for (int n = 0; n < 4; ++n) {
      const int c = c0 + n * 16 + l15;
      const float bv = b3[c];
#pragma unroll
      for (int m = 0; m < 2; ++m)
#pragma unroll
        for (int j = 0; j < 4; ++j) {
          const int el = r0 + m * 16 + (lane >> 4) * 4 + j;
          unsafeAtomicAdd(&aggr[(size_t)cols_s[el] * ND + c], acc[m][n][j] + bv);
        }
    }
  }
}

__global__ __launch_bounds__(256) void node_kernel(
    const float* __restrict__ x, const float* __restrict__ aggr,
    const ushort* __restrict__ Wtn1, const float* __restrict__ bn1,
    const ushort* __restrict__ Wtn2, const float* __restrict__ bn2,
    const float* __restrict__ gamma, const float* __restrict__ beta,
    float* __restrict__ out) {
  __shared__ __align__(16) ushort nfs[64 * 264];
  float* ys = reinterpret_cast<float*>(nfs);  // reused after MLP: y pre-LN, [64 x 132] f32
  const int tid = threadIdx.x;
  const int n0 = blockIdx.x * 64;
  {  // build [x | aggr] -> nfs bf16
    const int nl = tid >> 2, p = tid & 3;
    const int node = min(n0 + nl, NN - 1);
    ushort* dst = nfs + nl * 264;
    const float4* xr = reinterpret_cast<const float4*>(x + (size_t)node * ND) + p * 8;
    const float4* ar = reinterpret_cast<const float4*>(aggr + (size_t)node * ND) + p * 8;
#pragma unroll
    for (int j = 0; j < 8; ++j)
      *reinterpret_cast<ushort4*>(dst + p * 32 + j * 4) = f2b4(xr[j]);
#pragma unroll
    for (int j = 0; j < 8; ++j)
      *reinterpret_cast<ushort4*>(dst + 128 + p * 32 + j * 4) = f2b4(ar[j]);
  }
  __syncthreads();
  const int wave = tid >> 6, lane = tid & 63;
  layer256<256>(nfs, 264, Wtn1, bn1, nfs, 264, wave, lane);
  {  // layer n2: [64 x 256] -> [64 x 128], + bias + residual -> ys (f32)
    f32x4 acc[2][4] = {};
    const int r0 = (wave & 1) * 32;
    const int c0 = (wave >> 1) * 64;
    const int kb = (lane >> 4) * 8, l15 = lane & 15;
    for (int ks = 0; ks < 8; ++ks) {
      const int k = ks * 32 + kb;
      bf16x8 a[2], b[4];
#pragma unroll
      for (int m = 0; m < 2; ++m)
        a[m] = *reinterpret_cast<const bf16x8*>(nfs + (r0 + m * 16 + l15) * 264 + k);
#pragma unroll
      for (int n = 0; n < 4; ++n)
        b[n] = *reinterpret_cast<const bf16x8*>(Wtn2 + (size_t)(c0 + n * 16 + l15) * 256 + k);
#pragma unroll
      for (int m = 0; m < 2; ++m)
#pragma unroll
        for (int n = 0; n < 4; ++n)
          acc[m][n] = __builtin_amdgcn_mfma_f32_16x16x32_bf16(a[m], b[n], acc[m][n], 0, 0, 0);
    }
    __syncthreads();  // all waves done reading nfs; ys aliases nfs
#pragma unroll
    for (int n = 0; n < 4; ++n) {
      const int c = c0 + n * 16 + l15;
      const float bv = bn2[c];
#pragma unroll
      for (int m = 0; m < 2; ++m)
#pragma unroll
        for (int j = 0; j < 4; ++j) {
          const int el = r0 + m * 16 + (lane >> 4) * 4 + j;
          const int node = min(n0 + el, NN - 1);
          ys[el * 132 + c] = acc[m][n][j] + bv + x[(size_t)node * ND + c];
        }
    }
  }
  __syncthreads();
  {  // LayerNorm over 128 cols; 4 lanes per row
    const int row = tid >> 2, q = tid & 3;
    const float* yrow = ys + row * 132 + q * 32;
    float4 v[8];
    float s = 0.f, sq = 0.f;
#pragma unroll
    for (int j = 0; j < 8; ++j) {
      v[j] = reinterpret_cast<const float4*>(yrow)[j];
      s += v[j].x + v[j].y + v[j].z + v[j].w;
      sq += v[j].x * v[j].x + v[j].y * v[j].y + v[j].z * v[j].z + v[j].w * v[j].w;
    }
    s += __shfl_xor(s, 1); sq += __shfl_xor(sq, 1);
    s += __shfl_xor(s, 2); sq += __shfl_xor(sq, 2);
    const float mean = s * (1.f / 128.f);
    const float var = sq * (1.f / 128.f) - mean * mean;
    const float rs = rsqrtf(var + 1e-5f);
    const int node = n0 + row;
    if (node < NN) {
      float4* op = reinterpret_cast<float4*>(out + (size_t)node * ND + q * 32);
      const float4* g4 = reinterpret_cast<const float4*>(gamma + q * 32);
      const float4* bb4 = reinterpret_cast<const float4*>(beta + q * 32);
#pragma unroll
      for (int j = 0; j < 8; ++j) {
        const float4 g = g4[j], bb = bb4[j];
        float4 o;
        o.x = (v[j].x - mean) * rs * g.x + bb.x;
        o.y = (v[j].y - mean) * rs * g.y + bb.y;
        o.z = (v[j].z - mean) * rs * g.z + bb.z;
        o.w = (v[j].w - mean) * rs * g.w + bb.w;
        op[j] = o;
      }
    }
  }
}

// Wt[c*K + k] = bf16(W[k*C + c])  (transpose + convert)
__global__ __launch_bounds__(256) void wconv(const float* __restrict__ W,
                                             ushort* __restrict__ Wt, int K, int C) {
  const int idx = blockIdx.x * 256 + threadIdx.x;
  if (idx >= K * C) return;
  const int c = idx / K, k = idx - c * K;
  Wt[idx] = f2b(W[(size_t)k * C + c]);
}

extern "C" void kernel_launch(void* const* d_in, const int* in_sizes, int n_in,
                              void* d_out, int out_size, void* d_ws, size_t ws_size,
                              hipStream_t stream) {
  const float* x    = (const float*)d_in[0];
  const int*   ei   = (const int*)d_in[1];
  const float* ea   = (const float*)d_in[2];
  const float* W1   = (const float*)d_in[3];
  const float* b1   = (const float*)d_in[4];
  const float* W2   = (const float*)d_in[5];
  const float* b2   = (const float*)d_in[6];
  const float* W3   = (const float*)d_in[7];
  const float* b3   = (const float*)d_in[8];
  const float* Wn1  = (const float*)d_in[9];
  const float* bn1  = (const float*)d_in[10];
  const float* Wn2  = (const float*)d_in[11];
  const float* bn2  = (const float*)d_in[12];
  const float* gam  = (const float*)d_in[13];
  const float* bet  = (const float*)d_in[14];
  float* out = (float*)d_out;

  ushort* Wt1  = (ushort*)d_ws;            // 256 x 288
  ushort* Wt2  = Wt1 + 256 * 288;          // 256 x 256
  ushort* Wt3  = Wt2 + 256 * 256;          // 128 x 256
  ushort* Wtn1 = Wt3 + 128 * 256;          // 256 x 256
  ushort* Wtn2 = Wtn1 + 256 * 256;         // 128 x 256

  // aggr lives in d_out (read/written in disjoint per-block rows by node_kernel)
  hipMemsetAsync(d_out, 0, (size_t)out_size * sizeof(float), stream);
  wconv<<<(288 * 256 + 255) / 256, 256, 0, stream>>>(W1, Wt1, 288, 256);
  wconv<<<(256 * 256 + 255) / 256, 256, 0, stream>>>(W2, Wt2, 256, 256);
  wconv<<<(256 * 128 + 255) / 256, 256, 0, stream>>>(W3, Wt3, 256, 128);
  wconv<<<(256 * 256 + 255) / 256, 256, 0, stream>>>(Wn1, Wtn1, 256, 256);
  wconv<<<(256 * 128 + 255) / 256, 256, 0, stream>>>(Wn2, Wtn2, 256, 128);
  edge_kernel<<<EE / 64, 256, 0, stream>>>(x, ei, ea, Wt1, b1, Wt2, b2, Wt3, b3, out);
  node_kernel<<<(NN + 63) / 64, 256, 0, stream>>>(x, out, Wtn1, bn1, Wtn2, bn2, gam, bet, out);
}

// Round 4
// 870.636 us; speedup vs baseline: 1.0613x; 1.0613x over previous
//
#include <hip/hip_runtime.h>
#include <hip/hip_bf16.h>

#define NN 50000
#define EE 800000
#define ND 128
#define ED 32
#define HD 256

typedef __attribute__((ext_vector_type(8))) short bf16x8;
typedef __attribute__((ext_vector_type(4))) float f32x4;

__device__ __forceinline__ ushort f2b(float f) {
  union { float f; unsigned u; } v; v.f = f;
  return (ushort)((v.u + 0x7fffu + ((v.u >> 16) & 1u)) >> 16);
}

__device__ __forceinline__ ushort4 f2b4(float4 v) {
  return make_ushort4(f2b(v.x), f2b(v.y), f2b(v.z), f2b(v.w));
}

// MFMA layer over an LDS tile of MT*16 rows: in_lds [MT*16 x KDIM] bf16
// (stride in_stride), Wt [256 x KDIM] bf16 row-major (= original W transposed),
// bias f32[256]. Each wave computes ALL rows x its 64-col quadrant.
// Output: ReLU, bf16 -> out_lds (stride out_stride). May alias (barriers inside).
template<int KDIM, int MT>
__device__ __forceinline__ void layer_mfma(const ushort* __restrict__ in_lds, int in_stride,
                                           const ushort* __restrict__ wt,
                                           const float* __restrict__ bias,
                                           ushort* __restrict__ out_lds, int out_stride,
                                           int wave, int lane) {
  f32x4 acc[MT][4] = {};
  const int c0 = wave * 64;
  const int kb = (lane >> 4) * 8;
  const int l15 = lane & 15;
  for (int ks = 0; ks < KDIM / 32; ++ks) {
    const int k = ks * 32 + kb;
    bf16x8 a[MT], b[4];
#pragma unroll
    for (int n = 0; n < 4; ++n)
      b[n] = *reinterpret_cast<const bf16x8*>(wt + (size_t)(c0 + n * 16 + l15) * KDIM + k);
#pragma unroll
    for (int m = 0; m < MT; ++m)
      a[m] = *reinterpret_cast<const bf16x8*>(in_lds + (m * 16 + l15) * in_stride + k);
#pragma unroll
    for (int m = 0; m < MT; ++m)
#pragma unroll
      for (int n = 0; n < 4; ++n)
        acc[m][n] = __builtin_amdgcn_mfma_f32_16x16x32_bf16(a[m], b[n], acc[m][n], 0, 0, 0);
  }
  __syncthreads();  // all waves done reading in_lds (may alias out_lds)
#pragma unroll
  for (int n = 0; n < 4; ++n) {
    const int c = c0 + n * 16 + l15;
    const float bv = bias[c];
#pragma unroll
    for (int m = 0; m < MT; ++m)
#pragma unroll
      for (int j = 0; j < 4; ++j) {
        float v = acc[m][n][j] + bv;
        v = fmaxf(v, 0.f);
        out_lds[(m * 16 + (lane >> 4) * 4 + j) * out_stride + c] = f2b(v);
      }
  }
  __syncthreads();
}

// 128 edges per block, 4 waves. Each wave: M=128 x N=64 quadrant (acc[8][4]).
__global__ __launch_bounds__(256, 2) void edge_kernel(
    const float* __restrict__ x, const int* __restrict__ ei, const float* __restrict__ ea,
    const ushort* __restrict__ Wt1, const float* __restrict__ b1,
    const ushort* __restrict__ Wt2, const float* __restrict__ b2,
    const ushort* __restrict__ Wt3, const float* __restrict__ b3,
    float* __restrict__ aggr) {
  __shared__ __align__(16) ushort efs[128 * 296];
  __shared__ int rows_s[128], cols_s[128];
  const int tid = threadIdx.x;
  const int e0 = blockIdx.x * 128;
  if (tid < 128) {
    rows_s[tid] = ei[e0 + tid];
    cols_s[tid] = ei[EE + e0 + tid];
  }
  __syncthreads();
  {  // gather [x[row] | x[col] | edge_attr] -> efs bf16, 2 threads per edge
    const int el = tid >> 1, p = tid & 1;
    ushort* dst = efs + el * 296;
    const float4* xr = reinterpret_cast<const float4*>(x + (size_t)rows_s[el] * ND) + p * 16;
    const float4* xc = reinterpret_cast<const float4*>(x + (size_t)cols_s[el] * ND) + p * 16;
#pragma unroll
    for (int j = 0; j < 16; ++j)
      *reinterpret_cast<ushort4*>(dst + p * 64 + j * 4) = f2b4(xr[j]);
#pragma unroll
    for (int j = 0; j < 16; ++j)
      *reinterpret_cast<ushort4*>(dst + 128 + p * 64 + j * 4) = f2b4(xc[j]);
    const float4* eap = reinterpret_cast<const float4*>(ea + (size_t)(e0 + el) * ED) + p * 4;
#pragma unroll
    for (int j = 0; j < 4; ++j)
      *reinterpret_cast<ushort4*>(dst + 256 + p * 16 + j * 4) = f2b4(eap[j]);
  }
  __syncthreads();
  const int wave = tid >> 6, lane = tid & 63;
  layer_mfma<288, 8>(efs, 296, Wt1, b1, efs, 264, wave, lane);
  layer_mfma<256, 8>(efs, 264, Wt2, b2, efs, 264, wave, lane);
  {  // layer 3: [128 x 256] -> [128 x 128], then scatter-add to aggr[col]
    f32x4 acc[4][4] = {};
    const int r0 = (wave & 1) * 64;
    const int c0 = (wave >> 1) * 64;
    const int kb = (lane >> 4) * 8, l15 = lane & 15;
    for (int ks = 0; ks < 8; ++ks) {
      const int k = ks * 32 + kb;
      bf16x8 a[4], b[4];
#pragma unroll
      for (int n = 0; n < 4; ++n)
        b[n] = *reinterpret_cast<const bf16x8*>(Wt3 + (size_t)(c0 + n * 16 + l15) * 256 + k);
#pragma unroll
      for (int m = 0; m < 4; ++m)
        a[m] = *reinterpret_cast<const bf16x8*>(efs + (r0 + m * 16 + l15) * 264 + k);
#pragma unroll
      for (int m = 0; m < 4; ++m)
#pragma unroll
        for (int n = 0; n < 4; ++n)
          acc[m][n] = __builtin_amdgcn_mfma_f32_16x16x32_bf16(a[m], b[n], acc[m][n], 0, 0, 0);
    }
#pragma unroll
    for (int n = 0; n < 4; ++n) {
      const int c = c0 + n * 16 + l15;
      const float bv = b3[c];
#pragma unroll
      for (int m = 0; m < 4; ++m)
#pragma unroll
        for (int j = 0; j < 4; ++j) {
          const int el = r0 + m * 16 + (lane >> 4) * 4 + j;
          unsafeAtomicAdd(&aggr[(size_t)cols_s[el] * ND + c], acc[m][n][j] + bv);
        }
    }
  }
}

__global__ __launch_bounds__(256) void node_kernel(
    const float* __restrict__ x, const float* __restrict__ aggr,
    const ushort* __restrict__ Wtn1, const float* __restrict__ bn1,
    const ushort* __restrict__ Wtn2, const float* __restrict__ bn2,
    const float* __restrict__ gamma, const float* __restrict__ beta,
    float* __restrict__ out) {
  __shared__ __align__(16) ushort nfs[64 * 264];
  float* ys = reinterpret_cast<float*>(nfs);  // reused after MLP: y pre-LN, [64 x 132] f32
  const int tid = threadIdx.x;
  const int n0 = blockIdx.x * 64;
  {  // build [x | aggr] -> nfs bf16
    const int nl = tid >> 2, p = tid & 3;
    const int node = min(n0 + nl, NN - 1);
    ushort* dst = nfs + nl * 264;
    const float4* xr = reinterpret_cast<const float4*>(x + (size_t)node * ND) + p * 8;
    const float4* ar = reinterpret_cast<const float4*>(aggr + (size_t)node * ND) + p * 8;
#pragma unroll
    for (int j = 0; j < 8; ++j)
      *reinterpret_cast<ushort4*>(dst + p * 32 + j * 4) = f2b4(xr[j]);
#pragma unroll
    for (int j = 0; j < 8; ++j)
      *reinterpret_cast<ushort4*>(dst + 128 + p * 32 + j * 4) = f2b4(ar[j]);
  }
  __syncthreads();
  const int wave = tid >> 6, lane = tid & 63;
  layer_mfma<256, 4>(nfs, 264, Wtn1, bn1, nfs, 264, wave, lane);
  {  // layer n2: [64 x 256] -> [64 x 128], + bias + residual -> ys (f32)
    f32x4 acc[2][4] = {};
    const int r0 = (wave & 1) * 32;
    const int c0 = (wave >> 1) * 64;
    const int kb = (lane >> 4) * 8, l15 = lane & 15;
    for (int ks = 0; ks < 8; ++ks) {
      const int k = ks * 32 + kb;
      bf16x8 a[2], b[4];
#pragma unroll
      for (int m = 0; m < 2; ++m)
        a[m] = *reinterpret_cast<const bf16x8*>(nfs + (r0 + m * 16 + l15) * 264 + k);
#pragma unroll
      for (int n = 0; n < 4; ++n)
        b[n] = *reinterpret_cast<const bf16x8*>(Wtn2 + (size_t)(c0 + n * 16 + l15) * 256 + k);
#pragma unroll
      for (int m = 0; m < 2; ++m)
#pragma unroll
        for (int n = 0; n < 4; ++n)
          acc[m][n] = __builtin_amdgcn_mfma_f32_16x16x32_bf16(a[m], b[n], acc[m][n], 0, 0, 0);
    }
    __syncthreads();  // all waves done reading nfs; ys aliases nfs
#pragma unroll
    for (int n = 0; n < 4; ++n) {
      const int c = c0 + n * 16 + l15;
      const float bv = bn2[c];
#pragma unroll
      for (int m = 0; m < 2; ++m)
#pragma unroll
        for (int j = 0; j < 4; ++j) {
          const int el = r0 + m * 16 + (lane >> 4) * 4 + j;
          const int node = min(n0 + el, NN - 1);
          ys[el * 132 + c] = acc[m][n][j] + bv + x[(size_t)node * ND + c];
        }
    }
  }
  __syncthreads();
  {  // LayerNorm over 128 cols; 4 lanes per row
    const int row = tid >> 2, q = tid & 3;
    const float* yrow = ys + row * 132 + q * 32;
    float4 v[8];
    float s = 0.f, sq = 0.f;
#pragma unroll
    for (int j = 0; j < 8; ++j) {
      v[j] = reinterpret_cast<const float4*>(yrow)[j];
      s += v[j].x + v[j].y + v[j].z + v[j].w;
      sq += v[j].x * v[j].x + v[j].y * v[j].y + v[j].z * v[j].z + v[j].w * v[j].w;
    }
    s += __shfl_xor(s, 1); sq += __shfl_xor(sq, 1);
    s += __shfl_xor(s, 2); sq += __shfl_xor(sq, 2);
    const float mean = s * (1.f / 128.f);
    const float var = sq * (1.f / 128.f) - mean * mean;
    const float rs = rsqrtf(var + 1e-5f);
    const int node = n0 + row;
    if (node < NN) {
      float4* op = reinterpret_cast<float4*>(out + (size_t)node * ND + q * 32);
      const float4* g4 = reinterpret_cast<const float4*>(gamma + q * 32);
      const float4* bb4 = reinterpret_cast<const float4*>(beta + q * 32);
#pragma unroll
      for (int j = 0; j < 8; ++j) {
        const float4 g = g4[j], bb = bb4[j];
        float4 o;
        o.x = (v[j].x - mean) * rs * g.x + bb.x;
        o.y = (v[j].y - mean) * rs * g.y + bb.y;
        o.z = (v[j].z - mean) * rs * g.z + bb.z;
        o.w = (v[j].w - mean) * rs * g.w + bb.w;
        op[j] = o;
      }
    }
  }
}

// Wt[c*K + k] = bf16(W[k*C + c])  (transpose + convert)
__global__ __launch_bounds__(256) void wconv(const float* __restrict__ W,
                                             ushort* __restrict__ Wt, int K, int C) {
  const int idx = blockIdx.x * 256 + threadIdx.x;
  if (idx >= K * C) return;
  const int c = idx / K, k = idx - c * K;
  Wt[idx] = f2b(W[(size_t)k * C + c]);
}

extern "C" void kernel_launch(void* const* d_in, const int* in_sizes, int n_in,
                              void* d_out, int out_size, void* d_ws, size_t ws_size,
                              hipStream_t stream) {
  const float* x    = (const float*)d_in[0];
  const int*   ei   = (const int*)d_in[1];
  const float* ea   = (const float*)d_in[2];
  const float* W1   = (const float*)d_in[3];
  const float* b1   = (const float*)d_in[4];
  const float* W2   = (const float*)d_in[5];
  const float* b2   = (const float*)d_in[6];
  const float* W3   = (const float*)d_in[7];
  const float* b3   = (const float*)d_in[8];
  const float* Wn1  = (const float*)d_in[9];
  const float* bn1  = (const float*)d_in[10];
  const float* Wn2  = (const float*)d_in[11];
  const float* bn2  = (const float*)d_in[12];
  const float* gam  = (const float*)d_in[13];
  const float* bet  = (const float*)d_in[14];
  float* out = (float*)d_out;

  ushort* Wt1  = (ushort*)d_ws;            // 256 x 288
  ushort* Wt2  = Wt1 + 256 * 288;          // 256 x 256
  ushort* Wt3  = Wt2 + 256 * 256;          // 128 x 256
  ushort* Wtn1 = Wt3 + 128 * 256;          // 256 x 256
  ushort* Wtn2 = Wtn1 + 256 * 256;         // 128 x 256

  // aggr lives in d_out (read/written in disjoint per-block rows by node_kernel)
  hipMemsetAsync(d_out, 0, (size_t)out_size * sizeof(float), stream);
  wconv<<<(288 * 256 + 255) / 256, 256, 0, stream>>>(W1, Wt1, 288, 256);
  wconv<<<(256 * 256 + 255) / 256, 256, 0, stream>>>(W2, Wt2, 256, 256);
  wconv<<<(256 * 128 + 255) / 256, 256, 0, stream>>>(W3, Wt3, 256, 128);
  wconv<<<(256 * 256 + 255) / 256, 256, 0, stream>>>(Wn1, Wtn1, 256, 256);
  wconv<<<(256 * 128 + 255) / 256, 256, 0, stream>>>(Wn2, Wtn2, 256, 128);
  edge_kernel<<<EE / 128, 256, 0, stream>>>(x, ei, ea, Wt1, b1, Wt2, b2, Wt3, b3, out);
  node_kernel<<<(NN + 63) / 64, 256, 0, stream>>>(x, out, Wtn1, bn1, Wtn2, bn2, gam, bet, out);
}